// Round 1
// baseline (145.156 us; speedup 1.0000x reference)
//
#include <hip/hip_runtime.h>

// HardPartPyramidPooling: x(16,256,32,16,11) fp32, labels(16,32,176) int,
// out(16,256,32,16) fp32.  out[n][c][s][p] = sum/cnt + max over positions with
// label p (0 if cnt==0).  Memory-bound: ~101 MB total traffic, floor ~16 us.

constexpr int C  = 256;
constexpr int S  = 32;
constexpr int HW = 176;   // 16*11
constexpr int P  = 16;
constexpr float NEG_FILL = -100.0f;

// Block = one (n,s) slab; thread = channel.
// LDS accumulators [bank][part][tid]: word index % 32 == tid % 32 -> conflict-free.
// 2 banks (element parity) halve the per-lane LDS RMW latency chain.
__global__ __launch_bounds__(256) void hpp_kernel(
    const float* __restrict__ x,
    const int*   __restrict__ labels,
    float*       __restrict__ out)
{
    __shared__ float s_sum[2][P][C];   // 32 KB
    __shared__ float s_max[2][P][C];   // 32 KB
    __shared__ int   s_lbl[HW];
    __shared__ int   s_cnt[P];

    const int tid = threadIdx.x;
    const int blk = blockIdx.x;        // ns = n*S + s
    const int n   = blk >> 5;          // / S
    const int s   = blk & (S - 1);

    // init accumulators (each thread owns its column)
    #pragma unroll
    for (int p = 0; p < P; ++p) {
        s_sum[0][p][tid] = 0.0f;  s_sum[1][p][tid] = 0.0f;
        s_max[0][p][tid] = NEG_FILL; s_max[1][p][tid] = NEG_FILL;
    }
    if (tid < P) s_cnt[tid] = 0;
    __syncthreads();

    if (tid < HW) {
        int l = labels[blk * HW + tid];
        s_lbl[tid] = l;
        atomicAdd(&s_cnt[l], 1);
    }
    __syncthreads();

    // per-lane sequential float4 walk of this channel's 704 B row:
    // every fetched line fully consumed within 4 consecutive iterations (L1-hit).
    const float4* __restrict__ row =
        (const float4*)(x + ((((size_t)n * C + tid) * S + s) * HW));

    #pragma unroll 4
    for (int v = 0; v < HW / 4; ++v) {
        float4 val = row[v];
        int base = v * 4;
        int l0 = s_lbl[base + 0];
        int l1 = s_lbl[base + 1];
        int l2 = s_lbl[base + 2];
        int l3 = s_lbl[base + 3];
        // two independent RMW chains via bank parity
        s_sum[0][l0][tid] += val.x;
        s_max[0][l0][tid] = fmaxf(s_max[0][l0][tid], val.x);
        s_sum[1][l1][tid] += val.y;
        s_max[1][l1][tid] = fmaxf(s_max[1][l1][tid], val.y);
        s_sum[0][l2][tid] += val.z;
        s_max[0][l2][tid] = fmaxf(s_max[0][l2][tid], val.z);
        s_sum[1][l3][tid] += val.w;
        s_max[1][l3][tid] = fmaxf(s_max[1][l3][tid], val.w);
    }

    // no __syncthreads needed: each thread reads back only its own column,
    // and s_cnt/s_lbl were synced above.
    float res[P];
    #pragma unroll
    for (int p = 0; p < P; ++p) {
        int   cnt = s_cnt[p];
        float sum = s_sum[0][p][tid] + s_sum[1][p][tid];
        float mx  = fmaxf(s_max[0][p][tid], s_max[1][p][tid]);
        res[p] = (cnt > 0) ? (sum / (float)cnt + mx) : 0.0f;
    }

    // out[n][c][s][p], c = tid: 16 contiguous floats, 64 B aligned.
    float4* o = (float4*)(out + ((((size_t)n * C + tid) * S + s) * P));
    #pragma unroll
    for (int q = 0; q < 4; ++q)
        o[q] = make_float4(res[4*q+0], res[4*q+1], res[4*q+2], res[4*q+3]);
}

extern "C" void kernel_launch(void* const* d_in, const int* in_sizes, int n_in,
                              void* d_out, int out_size, void* d_ws, size_t ws_size,
                              hipStream_t stream) {
    const float* x      = (const float*)d_in[0];
    const int*   labels = (const int*)d_in[1];
    float*       out    = (float*)d_out;

    const int ns = in_sizes[1] / HW;   // 512
    hpp_kernel<<<ns, C, 0, stream>>>(x, labels, out);
}